// Round 6
// baseline (362.087 us; speedup 1.0000x reference)
//
#include <hip/hip_runtime.h>

#define T_ 32
#define S_ 4096
#define F_ 256
#define A_ 64
#define NS 2                     // s-values per iteration
#define GRID 256                 // persistent blocks, 1 per CU
#define ITERS (S_ / NS / GRID)   // 8

typedef __attribute__((ext_vector_type(8))) short s8v;   // 8 x bf16 (MFMA A/B frag)
typedef __attribute__((ext_vector_type(4))) float f4v;   // 4 x f32  (MFMA C/D frag)
typedef __attribute__((ext_vector_type(4))) short s4v;   // 8-byte packed store

#define MFMA(a, b, c) __builtin_amdgcn_mfma_f32_16x16x32_bf16((a), (b), (c), 0, 0, 0)

__device__ __forceinline__ unsigned short f2bf(float f) {
    unsigned int u = __builtin_bit_cast(unsigned int, f);
    u += 0x7FFFu + ((u >> 16) & 1u);   // round-to-nearest-even
    return (unsigned short)(u >> 16);
}

// ---- pre-pass: convert Wa[64x256], Wb[64x256], Wg[256x256] f32 -> bf16 in d_ws ----
__global__ void convert_weights(const float* __restrict__ Wa,
                                const float* __restrict__ Wb,
                                const float* __restrict__ Wg,
                                unsigned short* __restrict__ wsB)
{
    int base = (blockIdx.x * 256 + threadIdx.x) * 4;     // 24576 threads x 4 elems
    const float* src;
    if (base < 16384)      src = Wa + base;
    else if (base < 32768) src = Wb + (base - 16384);
    else                   src = Wg + (base - 32768);
    float4 v = *(const float4*)src;
    s4v p;
    p[0] = (short)f2bf(v.x); p[1] = (short)f2bf(v.y);
    p[2] = (short)f2bf(v.z); p[3] = (short)f2bf(v.w);
    *(s4v*)(wsB + base) = p;
}

// LDS layout (118784 B, 1 block/CU, 512 threads = 8 waves = 2 waves/SIMD):
//   [0, 32768)        X buf0 [64 rows (sl*32+t)][256] bf16, 512 B rows, swz (c+r)&31
//   [32768, 65536)    X buf1 (double buffer)
//   [65536, 73728)    theta [64][64] bf16, 128 B rows, swz (c+r)&7
//   [73728, 81920)    phi   [64][64] bf16
//   [81920, 86016)    attn  [64][32] bf16, 64 B rows, swz (c+r)&3
//   [86016, 118784)   featsT: per-wave 4 KB: [2 sl][32 f-local][32 u] bf16 (wave-private)
#define X0_OFF 0
#define X1_OFF 32768
#define TH_OFF 65536
#define PH_OFF 73728
#define AT_OFF 81920
#define FT_OFF 86016
#define LDS_BYTES 118784

// Custom barrier: lgkmcnt-only (cross-wave deps are LDS-only). __syncthreads would
// drain vmcnt(0) and kill the cross-iteration X register prefetch. sched_barrier(0)
// per rule #18 pins code motion.
#define BAR() do {                                            \
    asm volatile("s_waitcnt lgkmcnt(0)" ::: "memory");        \
    __builtin_amdgcn_s_barrier();                             \
    __builtin_amdgcn_sched_barrier(0);                        \
} while (0)

// (512,2): 8 waves, 2 per SIMD, VGPR cap 256. Persistent regs: wabfrag 32 + wg[2][8] 64
// + xnx 32 + biases; transients fa[2][4] 32 / ta[4] 16 / battn 16 -> peak ~210.
// History: VGPR caps of 102/128 forced weight re-fetch (spill or sink) every round;
// 1 wave/SIMD (round 5) exposed all latency (78% stall). This config fixes both.
__global__ __launch_bounds__(512, 2) void fused_temporal(
    const float* __restrict__ X,
    const unsigned short* __restrict__ wsB,
    const float* __restrict__ ba, const float* __restrict__ bb,
    const float* __restrict__ bg,
    float* __restrict__ out)
{
    __shared__ alignas(16) unsigned char smem[LDS_BYTES];
    const int tid  = threadIdx.x;
    const int wave = tid >> 6;          // 0..7
    const int lane = tid & 63;
    const int quad = lane >> 4;
    const int l15  = lane & 15;
    const int b    = blockIdx.x;

    const unsigned short* WgB = wsB + 32768;

    // ================= PROLOGUE (once per block) =================
    // theta/phi weights: wave w<4 -> Wa rows [16w,16w+16); wave w>=4 -> Wb rows [16(w-4),...)
    s8v wabfrag[8];
    {
        const unsigned short* p = wsB + (wave < 4 ? 0 : 16384)
                                + (size_t)(16 * (wave & 3) + l15) * F_ + quad * 8;
        #pragma unroll
        for (int ks = 0; ks < 8; ++ks) wabfrag[ks] = *(const s8v*)(p + ks * 32);
    }
    const float bias_ab = (wave < 4 ? ba : bb)[16 * (wave & 3) + l15];

    // feats weights: wave w owns f-cols [32w, 32w+32): wg[2][8] = 64 VGPR
    s8v wg[2][8];
    #pragma unroll
    for (int g = 0; g < 2; ++g) {
        const unsigned short* p = WgB + (size_t)(32 * wave + 16 * g + l15) * F_ + quad * 8;
        #pragma unroll
        for (int ks = 0; ks < 8; ++ks) wg[g][ks] = *(const s8v*)(p + ks * 32);
    }
    const float biasg[2] = { bg[32 * wave + l15], bg[32 * wave + 16 + l15] };

    // X for it=0 -> buf0
    {
        int s0 = b * NS;
        #pragma unroll
        for (int i = 0; i < 4; ++i) {
            int linear = i * 512 + tid;        // 0..2047 chunks of 8 f32
            int r = linear >> 5, c = linear & 31;
            int t = r & 31, sl = r >> 5;
            const float* xp = X + ((size_t)(t * S_ + s0 + sl)) * F_ + c * 8;
            float4 v0 = *(const float4*)(xp);
            float4 v1 = *(const float4*)(xp + 4);
            s8v p;
            p[0] = (short)f2bf(v0.x); p[1] = (short)f2bf(v0.y);
            p[2] = (short)f2bf(v0.z); p[3] = (short)f2bf(v0.w);
            p[4] = (short)f2bf(v1.x); p[5] = (short)f2bf(v1.y);
            p[6] = (short)f2bf(v1.z); p[7] = (short)f2bf(v1.w);
            *(s8v*)(&smem[X0_OFF + r * 512 + (((c + r) & 31) << 4)]) = p;
        }
    }
    BAR();

    // ================= PERSISTENT LOOP over s-pairs =================
    float4 xnx[8];
    #pragma unroll 1
    for (int it = 0; it < ITERS; ++it) {
        const int xs = (it & 1) ? X1_OFF : X0_OFF;
        const int xd = (it & 1) ? X0_OFF : X1_OFF;
        const int s0 = (it * GRID + b) * NS;

        // ---- issue next-iteration X loads (in flight across the whole iteration) ----
        if (it + 1 < ITERS) {
            int sn = ((it + 1) * GRID + b) * NS;
            #pragma unroll
            for (int i = 0; i < 4; ++i) {
                int linear = i * 512 + tid;
                int r = linear >> 5, c = linear & 31;
                int t = r & 31, sl = r >> 5;
                const float* xp = X + ((size_t)(t * S_ + sn + sl)) * F_ + c * 8;
                xnx[2 * i]     = *(const float4*)(xp);
                xnx[2 * i + 1] = *(const float4*)(xp + 4);
            }
        }

        // ---- Stage B: theta (waves 0-3) / phi (waves 4-7), 16 cols each, M=64 rows ----
        {
            f4v ac[4];
            #pragma unroll
            for (int mt = 0; mt < 4; ++mt) ac[mt] = f4v{0.f,0.f,0.f,0.f};
            #pragma unroll
            for (int ks = 0; ks < 8; ++ks) {
                int chunk = 4 * ks + quad;
                #pragma unroll
                for (int mt = 0; mt < 4; ++mt) {
                    int r = 16 * mt + l15;
                    s8v a = *(const s8v*)(&smem[xs + r * 512 + (((chunk + r) & 31) << 4)]);
                    ac[mt] = MFMA(a, wabfrag[ks], ac[mt]);
                }
            }
            const int dst = (wave < 4) ? TH_OFF : PH_OFF;
            int a_col = 16 * (wave & 3) + l15;
            int chunk = a_col >> 3;
            int sub   = (a_col & 7) * 2;
            #pragma unroll
            for (int mt = 0; mt < 4; ++mt) {
                #pragma unroll
                for (int r = 0; r < 4; ++r) {
                    int row = 16 * mt + quad * 4 + r;       // sl*32 + t
                    int sw  = ((chunk + row) & 7) << 4;
                    *(unsigned short*)(&smem[dst + row * 128 + sw + sub]) = f2bf(ac[mt][r] + bias_ab);
                }
            }
        }
        BAR();

        // ---- Attn: 8 tiles = 8 waves. wave: sl=w>>2, t-tile=(w>>1)&1, u-tile=w&1 ----
        {
            int sl  = wave >> 2;
            int mt2 = (wave >> 1) & 1;
            int nt2 = wave & 1;
            int t2  = l15 + 16 * mt2;
            int u2  = l15 + 16 * nt2;
            int rth = sl * 32 + t2;
            int rph = sl * 32 + u2;
            f4v acc2 = {0.f,0.f,0.f,0.f};
            #pragma unroll
            for (int ks = 0; ks < 2; ++ks) {
                int chunk = 4 * ks + quad;
                s8v av = *(const s8v*)(&smem[TH_OFF + rth * 128 + (((chunk + rth) & 7) << 4)]);
                s8v bv = *(const s8v*)(&smem[PH_OFF + rph * 128 + (((chunk + rph) & 7) << 4)]);
                acc2 = MFMA(av, bv, acc2);
            }
            int chunk = u2 >> 3;
            int sub   = (u2 & 7) * 2;
            #pragma unroll
            for (int r = 0; r < 4; ++r) {
                int tt  = quad * 4 + r + 16 * mt2;
                int rat = sl * 32 + tt;
                *(unsigned short*)(&smem[AT_OFF + rat * 64 + (((chunk + rat) & 3) << 4) + sub]) = f2bf(acc2[r]);
            }
        }
        BAR();

        // ---- Stage C/D: feats (wg regs) -> featsT (wave-private) -> PV -> out ----
        {
            s8v battn[2][2];
            #pragma unroll
            for (int sl = 0; sl < 2; ++sl) {
                #pragma unroll
                for (int nt = 0; nt < 2; ++nt) {
                    int rat = sl * 32 + l15 + 16 * nt;
                    battn[sl][nt] = *(const s8v*)(&smem[AT_OFF + rat * 64 + (((quad + rat) & 3) << 4)]);
                }
            }
            const int ftbase = FT_OFF + wave * 4096;   // [2 sl][32 f-local][32 u] bf16

            // ks-outer: one A-read feeds both g-groups
            f4v fa[2][4];
            #pragma unroll
            for (int g = 0; g < 2; ++g)
                #pragma unroll
                for (int mt = 0; mt < 4; ++mt) fa[g][mt] = f4v{0.f,0.f,0.f,0.f};
            #pragma unroll
            for (int ks = 0; ks < 8; ++ks) {
                int chunk = 4 * ks + quad;
                #pragma unroll
                for (int mt = 0; mt < 4; ++mt) {
                    int r = 16 * mt + l15;
                    s8v a = *(const s8v*)(&smem[xs + r * 512 + (((chunk + r) & 31) << 4)]);
                    fa[0][mt] = MFMA(a, wg[0][ks], fa[0][mt]);
                    fa[1][mt] = MFMA(a, wg[1][ks], fa[1][mt]);
                }
            }

            #pragma unroll
            for (int g = 0; g < 2; ++g) {
                int fl = 16 * g + l15;                      // f-local in [0,32)
                // featsT write: D row = 16mt+quad*4+r -> (sl=mt>>1, u=(mt&1)*16+quad*4+r)
                #pragma unroll
                for (int mt = 0; mt < 4; ++mt) {
                    int sl = mt >> 1;
                    int u0 = (mt & 1) * 16 + quad * 4;
                    s4v pk;
                    #pragma unroll
                    for (int r = 0; r < 4; ++r) pk[r] = (short)f2bf(fa[g][mt][r] + biasg[g]);
                    int addr = ftbase + sl * 2048 + fl * 64
                             + ((((u0 >> 3) + fl) & 3) << 4) + (u0 & 7) * 2;
                    *(s4v*)(&smem[addr]) = pk;              // ds_write_b64, wave-private
                }
                // PV: A-frag featsT[f-local=l15-row][u=quad*8+j]; D: col=l15->t, rows->4 consecutive f
                int f0 = 32 * wave + 16 * g + 4 * quad;
                #pragma unroll
                for (int sl = 0; sl < 2; ++sl) {
                    s8v avf = *(const s8v*)(&smem[ftbase + sl * 2048 + fl * 64 + (((quad + fl) & 3) << 4)]);
                    #pragma unroll
                    for (int nt = 0; nt < 2; ++nt) {
                        f4v z = {0.f,0.f,0.f,0.f};
                        f4v acc = MFMA(avf, battn[sl][nt], z);
                        int t = l15 + 16 * nt;
                        float4 st;
                        st.x = acc[0]; st.y = acc[1]; st.z = acc[2]; st.w = acc[3];
                        *(float4*)(out + ((size_t)(t * S_ + s0 + sl)) * F_ + f0) = st;
                    }
                }
            }
        }

        // ---- convert prefetched X into the other buffer ----
        if (it + 1 < ITERS) {
            #pragma unroll
            for (int i = 0; i < 4; ++i) {
                int linear = i * 512 + tid;
                int r = linear >> 5, c = linear & 31;
                float4 v0 = xnx[2 * i];
                float4 v1 = xnx[2 * i + 1];
                s8v p;
                p[0] = (short)f2bf(v0.x); p[1] = (short)f2bf(v0.y);
                p[2] = (short)f2bf(v0.z); p[3] = (short)f2bf(v0.w);
                p[4] = (short)f2bf(v1.x); p[5] = (short)f2bf(v1.y);
                p[6] = (short)f2bf(v1.z); p[7] = (short)f2bf(v1.w);
                *(s8v*)(&smem[xd + r * 512 + (((c + r) & 31) << 4)]) = p;
            }
        }
        BAR();   // X[xd] visible for next iteration's stage B
    }
}

extern "C" void kernel_launch(void* const* d_in, const int* in_sizes, int n_in,
                              void* d_out, int out_size, void* d_ws, size_t ws_size,
                              hipStream_t stream) {
    (void)in_sizes; (void)n_in; (void)ws_size; (void)out_size;
    const float* X  = (const float*)d_in[0];   // batch_data [T*S, F] f32
    // d_in[1] = xywh (dead path)
    const float* Wa = (const float*)d_in[2];
    const float* ba = (const float*)d_in[3];
    const float* Wb = (const float*)d_in[4];
    const float* bb = (const float*)d_in[5];
    const float* Wg = (const float*)d_in[6];
    const float* bg = (const float*)d_in[7];
    // d_in[8] = Wh, d_in[9] = bh (dead path)
    float* out = (float*)d_out;
    unsigned short* wsB = (unsigned short*)d_ws;   // 192 KB bf16 weights

    convert_weights<<<dim3(96), dim3(256), 0, stream>>>(Wa, Wb, Wg, wsB);
    fused_temporal<<<dim3(GRID), dim3(512), 0, stream>>>(X, wsB, ba, bb, bg, out);
}

// Round 7
// 356.231 us; speedup vs baseline: 1.0164x; 1.0164x over previous
//
#include <hip/hip_runtime.h>

#define T_ 32
#define S_ 4096
#define F_ 256
#define A_ 64
#define NS 2                     // s-values per iteration
#define GRID 256                 // persistent blocks, 1 per CU
#define ITERS (S_ / NS / GRID)   // 8

typedef __attribute__((ext_vector_type(8))) short s8v;   // 8 x bf16 (MFMA A/B frag)
typedef __attribute__((ext_vector_type(4))) float f4v;   // 4 x f32  (MFMA C/D frag)
typedef __attribute__((ext_vector_type(4))) short s4v;   // 8-byte packed store

#define MFMA(a, b, c) __builtin_amdgcn_mfma_f32_16x16x32_bf16((a), (b), (c), 0, 0, 0)

__device__ __forceinline__ unsigned short f2bf(float f) {
    unsigned int u = __builtin_bit_cast(unsigned int, f);
    u += 0x7FFFu + ((u >> 16) & 1u);   // round-to-nearest-even
    return (unsigned short)(u >> 16);
}

// ---- pre-pass: convert Wa[64x256], Wb[64x256], Wg[256x256] f32 -> bf16 in d_ws ----
__global__ void convert_weights(const float* __restrict__ Wa,
                                const float* __restrict__ Wb,
                                const float* __restrict__ Wg,
                                unsigned short* __restrict__ wsB)
{
    int base = (blockIdx.x * 256 + threadIdx.x) * 4;     // 24576 threads x 4 elems
    const float* src;
    if (base < 16384)      src = Wa + base;
    else if (base < 32768) src = Wb + (base - 16384);
    else                   src = Wg + (base - 32768);
    float4 v = *(const float4*)src;
    s4v p;
    p[0] = (short)f2bf(v.x); p[1] = (short)f2bf(v.y);
    p[2] = (short)f2bf(v.z); p[3] = (short)f2bf(v.w);
    *(s4v*)(wsB + base) = p;
}

// LDS layout (118784 B, 1 block/CU, 512 threads = 8 waves = 2 waves/SIMD):
//   [0, 32768)        X buf0 [64 rows (sl*32+t)][256] bf16, 512 B rows, swz (c+r)&31
//   [32768, 65536)    X buf1 (double buffer)
//   [65536, 73728)    theta [64][64] bf16, 128 B rows, swz (c+r)&7
//   [73728, 81920)    phi   [64][64] bf16
//   [81920, 86016)    attn  [64][32] bf16, 64 B rows, swz (c+r)&3
//   [86016, 118784)   featsT: per-wave 4 KB: [2 sl][32 f-local][32 u] bf16 (wave-private)
#define X0_OFF 0
#define X1_OFF 32768
#define TH_OFF 65536
#define PH_OFF 73728
#define AT_OFF 81920
#define FT_OFF 86016
#define LDS_BYTES 118784

// Custom barrier: lgkmcnt-only (cross-wave deps are LDS-only). __syncthreads would
// drain vmcnt(0) and kill the cross-iteration X register prefetch. sched_barrier(0)
// per rule #18 pins code motion.
#define BAR() do {                                            \
    asm volatile("s_waitcnt lgkmcnt(0)" ::: "memory");        \
    __builtin_amdgcn_s_barrier();                             \
    __builtin_amdgcn_sched_barrier(0);                        \
} while (0)

// *** MEASURED TOOLCHAIN SEMANTICS (rounds 1-6): the 2nd __launch_bounds__ arg acts
// as min BLOCKS PER CU (CUDA-style), not waves-per-EU: (256,5)->cap102, (256,4)->128,
// (256,3)->170, (512,2)->128 (spilled persistent weights, +75MB scratch traffic).
// (512,1): 1 block x 8 waves = 2 waves/SIMD, cap 256. Persistent regs: wabfrag 32 +
// wg[2][8] 64 = 96; peak ~210 with xnx prefetch. Must NOT spill: check VGPR~250 &
// hbm_bytes ~2.2e8.
__global__ __launch_bounds__(512, 1) void fused_temporal(
    const float* __restrict__ X,
    const unsigned short* __restrict__ wsB,
    const float* __restrict__ ba, const float* __restrict__ bb,
    const float* __restrict__ bg,
    float* __restrict__ out)
{
    __shared__ alignas(16) unsigned char smem[LDS_BYTES];
    const int tid  = threadIdx.x;
    const int wave = tid >> 6;          // 0..7
    const int lane = tid & 63;
    const int quad = lane >> 4;
    const int l15  = lane & 15;
    const int b    = blockIdx.x;

    const unsigned short* WgB = wsB + 32768;

    // ================= PROLOGUE (once per block) =================
    // theta/phi weights: wave w<4 -> Wa rows [16w,16w+16); wave w>=4 -> Wb rows [16(w-4),...)
    s8v wabfrag[8];
    {
        const unsigned short* p = wsB + (wave < 4 ? 0 : 16384)
                                + (size_t)(16 * (wave & 3) + l15) * F_ + quad * 8;
        #pragma unroll
        for (int ks = 0; ks < 8; ++ks) wabfrag[ks] = *(const s8v*)(p + ks * 32);
    }
    const float bias_ab = (wave < 4 ? ba : bb)[16 * (wave & 3) + l15];

    // feats weights: wave w owns f-cols [32w, 32w+32): wg[2][8] = 64 VGPR
    s8v wg[2][8];
    #pragma unroll
    for (int g = 0; g < 2; ++g) {
        const unsigned short* p = WgB + (size_t)(32 * wave + 16 * g + l15) * F_ + quad * 8;
        #pragma unroll
        for (int ks = 0; ks < 8; ++ks) wg[g][ks] = *(const s8v*)(p + ks * 32);
    }
    const float biasg[2] = { bg[32 * wave + l15], bg[32 * wave + 16 + l15] };

    // X for it=0 -> buf0
    {
        int s0 = b * NS;
        #pragma unroll
        for (int i = 0; i < 4; ++i) {
            int linear = i * 512 + tid;        // 0..2047 chunks of 8 f32
            int r = linear >> 5, c = linear & 31;
            int t = r & 31, sl = r >> 5;
            const float* xp = X + ((size_t)(t * S_ + s0 + sl)) * F_ + c * 8;
            float4 v0 = *(const float4*)(xp);
            float4 v1 = *(const float4*)(xp + 4);
            s8v p;
            p[0] = (short)f2bf(v0.x); p[1] = (short)f2bf(v0.y);
            p[2] = (short)f2bf(v0.z); p[3] = (short)f2bf(v0.w);
            p[4] = (short)f2bf(v1.x); p[5] = (short)f2bf(v1.y);
            p[6] = (short)f2bf(v1.z); p[7] = (short)f2bf(v1.w);
            *(s8v*)(&smem[X0_OFF + r * 512 + (((c + r) & 31) << 4)]) = p;
        }
    }
    BAR();

    // ================= PERSISTENT LOOP over s-pairs =================
    float4 xnx[8];
    #pragma unroll 1
    for (int it = 0; it < ITERS; ++it) {
        const int xs = (it & 1) ? X1_OFF : X0_OFF;
        const int xd = (it & 1) ? X0_OFF : X1_OFF;
        const int s0 = (it * GRID + b) * NS;

        // ---- issue next-iteration X loads (in flight across the whole iteration) ----
        if (it + 1 < ITERS) {
            int sn = ((it + 1) * GRID + b) * NS;
            #pragma unroll
            for (int i = 0; i < 4; ++i) {
                int linear = i * 512 + tid;
                int r = linear >> 5, c = linear & 31;
                int t = r & 31, sl = r >> 5;
                const float* xp = X + ((size_t)(t * S_ + sn + sl)) * F_ + c * 8;
                xnx[2 * i]     = *(const float4*)(xp);
                xnx[2 * i + 1] = *(const float4*)(xp + 4);
            }
        }

        // ---- Stage B: theta (waves 0-3) / phi (waves 4-7), 16 cols each, M=64 rows ----
        {
            f4v ac[4];
            #pragma unroll
            for (int mt = 0; mt < 4; ++mt) ac[mt] = f4v{0.f,0.f,0.f,0.f};
            #pragma unroll
            for (int ks = 0; ks < 8; ++ks) {
                int chunk = 4 * ks + quad;
                #pragma unroll
                for (int mt = 0; mt < 4; ++mt) {
                    int r = 16 * mt + l15;
                    s8v a = *(const s8v*)(&smem[xs + r * 512 + (((chunk + r) & 31) << 4)]);
                    ac[mt] = MFMA(a, wabfrag[ks], ac[mt]);
                }
            }
            const int dst = (wave < 4) ? TH_OFF : PH_OFF;
            int a_col = 16 * (wave & 3) + l15;
            int chunk = a_col >> 3;
            int sub   = (a_col & 7) * 2;
            #pragma unroll
            for (int mt = 0; mt < 4; ++mt) {
                #pragma unroll
                for (int r = 0; r < 4; ++r) {
                    int row = 16 * mt + quad * 4 + r;       // sl*32 + t
                    int sw  = ((chunk + row) & 7) << 4;
                    *(unsigned short*)(&smem[dst + row * 128 + sw + sub]) = f2bf(ac[mt][r] + bias_ab);
                }
            }
        }
        BAR();

        // ---- Attn: 8 tiles = 8 waves. wave: sl=w>>2, t-tile=(w>>1)&1, u-tile=w&1 ----
        {
            int sl  = wave >> 2;
            int mt2 = (wave >> 1) & 1;
            int nt2 = wave & 1;
            int t2  = l15 + 16 * mt2;
            int u2  = l15 + 16 * nt2;
            int rth = sl * 32 + t2;
            int rph = sl * 32 + u2;
            f4v acc2 = {0.f,0.f,0.f,0.f};
            #pragma unroll
            for (int ks = 0; ks < 2; ++ks) {
                int chunk = 4 * ks + quad;
                s8v av = *(const s8v*)(&smem[TH_OFF + rth * 128 + (((chunk + rth) & 7) << 4)]);
                s8v bv = *(const s8v*)(&smem[PH_OFF + rph * 128 + (((chunk + rph) & 7) << 4)]);
                acc2 = MFMA(av, bv, acc2);
            }
            int chunk = u2 >> 3;
            int sub   = (u2 & 7) * 2;
            #pragma unroll
            for (int r = 0; r < 4; ++r) {
                int tt  = quad * 4 + r + 16 * mt2;
                int rat = sl * 32 + tt;
                *(unsigned short*)(&smem[AT_OFF + rat * 64 + (((chunk + rat) & 3) << 4) + sub]) = f2bf(acc2[r]);
            }
        }
        BAR();

        // ---- Stage C/D: feats (wg regs) -> featsT (wave-private) -> PV -> out ----
        {
            s8v battn[2][2];
            #pragma unroll
            for (int sl = 0; sl < 2; ++sl) {
                #pragma unroll
                for (int nt = 0; nt < 2; ++nt) {
                    int rat = sl * 32 + l15 + 16 * nt;
                    battn[sl][nt] = *(const s8v*)(&smem[AT_OFF + rat * 64 + (((quad + rat) & 3) << 4)]);
                }
            }
            const int ftbase = FT_OFF + wave * 4096;   // [2 sl][32 f-local][32 u] bf16

            // ks-outer: one A-read feeds both g-groups
            f4v fa[2][4];
            #pragma unroll
            for (int g = 0; g < 2; ++g)
                #pragma unroll
                for (int mt = 0; mt < 4; ++mt) fa[g][mt] = f4v{0.f,0.f,0.f,0.f};
            #pragma unroll
            for (int ks = 0; ks < 8; ++ks) {
                int chunk = 4 * ks + quad;
                #pragma unroll
                for (int mt = 0; mt < 4; ++mt) {
                    int r = 16 * mt + l15;
                    s8v a = *(const s8v*)(&smem[xs + r * 512 + (((chunk + r) & 31) << 4)]);
                    fa[0][mt] = MFMA(a, wg[0][ks], fa[0][mt]);
                    fa[1][mt] = MFMA(a, wg[1][ks], fa[1][mt]);
                }
            }

            #pragma unroll
            for (int g = 0; g < 2; ++g) {
                int fl = 16 * g + l15;                      // f-local in [0,32)
                // featsT write: D row = 16mt+quad*4+r -> (sl=mt>>1, u=(mt&1)*16+quad*4+r)
                #pragma unroll
                for (int mt = 0; mt < 4; ++mt) {
                    int sl = mt >> 1;
                    int u0 = (mt & 1) * 16 + quad * 4;
                    s4v pk;
                    #pragma unroll
                    for (int r = 0; r < 4; ++r) pk[r] = (short)f2bf(fa[g][mt][r] + biasg[g]);
                    int addr = ftbase + sl * 2048 + fl * 64
                             + ((((u0 >> 3) + fl) & 3) << 4) + (u0 & 7) * 2;
                    *(s4v*)(&smem[addr]) = pk;              // ds_write_b64, wave-private
                }
                // PV: A-frag featsT[f-local=l15-row][u=quad*8+j]; D: col=l15->t, rows->4 consecutive f
                int f0 = 32 * wave + 16 * g + 4 * quad;
                #pragma unroll
                for (int sl = 0; sl < 2; ++sl) {
                    s8v avf = *(const s8v*)(&smem[ftbase + sl * 2048 + fl * 64 + (((quad + fl) & 3) << 4)]);
                    #pragma unroll
                    for (int nt = 0; nt < 2; ++nt) {
                        f4v z = {0.f,0.f,0.f,0.f};
                        f4v acc = MFMA(avf, battn[sl][nt], z);
                        int t = l15 + 16 * nt;
                        float4 st;
                        st.x = acc[0]; st.y = acc[1]; st.z = acc[2]; st.w = acc[3];
                        *(float4*)(out + ((size_t)(t * S_ + s0 + sl)) * F_ + f0) = st;
                    }
                }
            }
        }

        // ---- convert prefetched X into the other buffer ----
        if (it + 1 < ITERS) {
            #pragma unroll
            for (int i = 0; i < 4; ++i) {
                int linear = i * 512 + tid;
                int r = linear >> 5, c = linear & 31;
                float4 v0 = xnx[2 * i];
                float4 v1 = xnx[2 * i + 1];
                s8v p;
                p[0] = (short)f2bf(v0.x); p[1] = (short)f2bf(v0.y);
                p[2] = (short)f2bf(v0.z); p[3] = (short)f2bf(v0.w);
                p[4] = (short)f2bf(v1.x); p[5] = (short)f2bf(v1.y);
                p[6] = (short)f2bf(v1.z); p[7] = (short)f2bf(v1.w);
                *(s8v*)(&smem[xd + r * 512 + (((c + r) & 31) << 4)]) = p;
            }
        }
        BAR();   // X[xd] visible for next iteration's stage B
    }
}

extern "C" void kernel_launch(void* const* d_in, const int* in_sizes, int n_in,
                              void* d_out, int out_size, void* d_ws, size_t ws_size,
                              hipStream_t stream) {
    (void)in_sizes; (void)n_in; (void)ws_size; (void)out_size;
    const float* X  = (const float*)d_in[0];   // batch_data [T*S, F] f32
    // d_in[1] = xywh (dead path)
    const float* Wa = (const float*)d_in[2];
    const float* ba = (const float*)d_in[3];
    const float* Wb = (const float*)d_in[4];
    const float* bb = (const float*)d_in[5];
    const float* Wg = (const float*)d_in[6];
    const float* bg = (const float*)d_in[7];
    // d_in[8] = Wh, d_in[9] = bh (dead path)
    float* out = (float*)d_out;
    unsigned short* wsB = (unsigned short*)d_ws;   // 192 KB bf16 weights

    convert_weights<<<dim3(96), dim3(256), 0, stream>>>(Wa, Wb, Wg, wsB);
    fused_temporal<<<dim3(GRID), dim3(512), 0, stream>>>(X, wsB, ba, bb, bg, out);
}